// Round 1
// baseline (528.316 us; speedup 1.0000x reference)
//
#include <hip/hip_runtime.h>
#include <math.h>

#define HH 8
#define CC 32
#define DD 128
#define HC 256
#define II 128
#define LL 256
#define NROW (II*LL)   // 32768
#define LN_EPS 1e-5f
#define BM 64
#define BN 64

// ---------------- K1: LayerNorm over last dim (D=128), one block per row ----
__global__ __launch_bounds__(128) void k_ln(const float* __restrict__ z,
                                            const float* __restrict__ gamma,
                                            const float* __restrict__ beta,
                                            float* __restrict__ zn)
{
    const int row = blockIdx.x;
    const int t = threadIdx.x;
    __shared__ float red[128];
    float x = z[(size_t)row * DD + t];
    red[t] = x;
    __syncthreads();
    for (int s = 64; s > 0; s >>= 1) {
        if (t < s) red[t] += red[t + s];
        __syncthreads();
    }
    float mu = red[0] * (1.0f / DD);
    __syncthreads();
    float d = x - mu;
    red[t] = d * d;
    __syncthreads();
    for (int s = 64; s > 0; s >>= 1) {
        if (t < s) red[t] += red[t + s];
        __syncthreads();
    }
    float rstd = rsqrtf(red[0] * (1.0f / DD) + LN_EPS);
    zn[(size_t)row * DD + t] = d * rstd * gamma[t] + beta[t];
}

// ---------------- K2: projections GEMM: zn[32768x128] @ W[128x1024] --------
// cols 0..255 -> q (scaled), 256..511 -> k, 512..767 -> v, 768..1023 -> g (sigmoid)
// Output P[row][1024].
__global__ __launch_bounds__(256) void k_proj(const float* __restrict__ zn,
                                              const float* __restrict__ Wq,
                                              const float* __restrict__ Wk,
                                              const float* __restrict__ Wv,
                                              const float* __restrict__ Wg,
                                              const float* __restrict__ bg,
                                              float* __restrict__ P)
{
    const int rb = blockIdx.x;      // 512 row blocks of 64
    const int cb = blockIdx.y;      // 16 col blocks of 64
    const int t  = threadIdx.x;
    __shared__ float As[DD][BM + 1];   // A^T: [k][m], padded
    __shared__ float Bs[DD][BN];       // [k][n]
    const int row0 = rb * BM;
    const int colg = cb * BN;          // global col in [0,1024)
    const int mat  = colg >> 8;        // 0..3 (uniform per block)
    const int lc0  = colg & 255;       // local col within that matrix
    const float* W = (mat == 0) ? Wq : (mat == 1) ? Wk : (mat == 2) ? Wv : Wg;

#pragma unroll
    for (int e = 0; e < 32; ++e) {       // 64x128 A tile
        int idx = e * 256 + t;
        int m = idx >> 7, k = idx & 127;
        As[k][m] = zn[(size_t)(row0 + m) * DD + k];
    }
#pragma unroll
    for (int e = 0; e < 32; ++e) {       // 128x64 B tile
        int idx = e * 256 + t;
        int k = idx >> 6, n = idx & 63;
        Bs[k][n] = W[(size_t)k * HC + lc0 + n];
    }
    __syncthreads();

    const int tx = t & 15, ty = t >> 4;
    float acc[4][4];
#pragma unroll
    for (int a = 0; a < 4; ++a)
#pragma unroll
        for (int b = 0; b < 4; ++b) acc[a][b] = 0.0f;

    for (int k = 0; k < DD; ++k) {
        float4 av = *(const float4*)&As[k][ty * 4];
        float4 bv = *(const float4*)&Bs[k][tx * 4];
        float aa[4] = {av.x, av.y, av.z, av.w};
        float bb[4] = {bv.x, bv.y, bv.z, bv.w};
#pragma unroll
        for (int a = 0; a < 4; ++a)
#pragma unroll
            for (int b = 0; b < 4; ++b) acc[a][b] += aa[a] * bb[b];
    }

#pragma unroll
    for (int a = 0; a < 4; ++a) {
        int row = row0 + ty * 4 + a;
#pragma unroll
        for (int b = 0; b < 4; ++b) {
            int lc = lc0 + tx * 4 + b;
            float v = acc[a][b];
            if (mat == 0) v *= 0.35355339059327373f;       // H^-0.5
            else if (mat == 3) v = 1.0f / (1.0f + __expf(-(v + bg[lc])));
            P[(size_t)row * 1024 + (mat << 8) + lc] = v;
        }
    }
}

// ---------------- K3: attention per (i,h), online softmax ------------------
// P layout per row: [0:256)=q(scaled) [256:512)=k [512:768)=v [768:1024)=g
// Writes gated output in place into the q slot (own head's 32 cols only).
__global__ __launch_bounds__(256) void k_attn(const float* __restrict__ P_in,
                                              float* __restrict__ P_out,
                                              const float* __restrict__ djk,
                                              const float* __restrict__ Wd,
                                              const float* __restrict__ mask)
{
    const int i = blockIdx.x;   // 0..127
    const int h = blockIdx.y;   // 0..7
    const int t = threadIdx.x;  // q index 0..255
    __shared__ float ks[LL][CC];
    __shared__ float vs[LL][CC];
    __shared__ float madd[LL];
    const size_t rowbase = (size_t)i * LL * 1024;
    const int hoff = h * CC;

#pragma unroll
    for (int e = 0; e < 32; ++e) {
        int idx = e * 256 + t;
        int l = idx >> 5, c = idx & 31;
        ks[l][c] = P_in[rowbase + (size_t)l * 1024 + 256 + hoff + c];
        vs[l][c] = P_in[rowbase + (size_t)l * 1024 + 512 + hoff + c];
    }
    madd[t] = 1e9f * (mask[i * LL + t] - 1.0f);

    float qreg[CC];
    {
        const float4* qr = (const float4*)(P_in + rowbase + (size_t)t * 1024 + hoff);
#pragma unroll
        for (int c4 = 0; c4 < CC / 4; ++c4) {
            float4 qv = qr[c4];
            qreg[c4 * 4 + 0] = qv.x; qreg[c4 * 4 + 1] = qv.y;
            qreg[c4 * 4 + 2] = qv.z; qreg[c4 * 4 + 3] = qv.w;
        }
    }
    __syncthreads();

    const float wd = Wd[h];
    const float4* drow4 = (const float4*)(djk + (size_t)t * LL);
    float m = -3.0e38f, ssum = 0.0f;
    float acc[CC];
#pragma unroll
    for (int c = 0; c < CC; ++c) acc[c] = 0.0f;

    for (int k4 = 0; k4 < LL / 4; ++k4) {
        float4 dv = drow4[k4];
        float dvals[4] = {dv.x, dv.y, dv.z, dv.w};
#pragma unroll
        for (int u = 0; u < 4; ++u) {
            int k = k4 * 4 + u;
            float s = wd * dvals[u] + madd[k];
            const float4* kr = (const float4*)&ks[k][0];
#pragma unroll
            for (int c4 = 0; c4 < CC / 4; ++c4) {
                float4 kv = kr[c4];
                s += qreg[c4 * 4 + 0] * kv.x + qreg[c4 * 4 + 1] * kv.y
                   + qreg[c4 * 4 + 2] * kv.z + qreg[c4 * 4 + 3] * kv.w;
            }
            float mn = fmaxf(m, s);
            float sc = __expf(m - mn);   // 0 on first iteration
            float w  = __expf(s - mn);
            m = mn;
            ssum = ssum * sc + w;
            const float4* vr = (const float4*)&vs[k][0];
#pragma unroll
            for (int c4 = 0; c4 < CC / 4; ++c4) {
                float4 vv = vr[c4];
                acc[c4 * 4 + 0] = acc[c4 * 4 + 0] * sc + w * vv.x;
                acc[c4 * 4 + 1] = acc[c4 * 4 + 1] * sc + w * vv.y;
                acc[c4 * 4 + 2] = acc[c4 * 4 + 2] * sc + w * vv.z;
                acc[c4 * 4 + 3] = acc[c4 * 4 + 3] * sc + w * vv.w;
            }
        }
    }

    float inv = 1.0f / ssum;
    {
        const float4* gr = (const float4*)(P_in + rowbase + (size_t)t * 1024 + 768 + hoff);
#pragma unroll
        for (int c4 = 0; c4 < CC / 4; ++c4) {
            float4 gv = gr[c4];
            P_out[rowbase + (size_t)t * 1024 + hoff + c4 * 4 + 0] = gv.x * acc[c4 * 4 + 0] * inv;
            P_out[rowbase + (size_t)t * 1024 + hoff + c4 * 4 + 1] = gv.y * acc[c4 * 4 + 1] * inv;
            P_out[rowbase + (size_t)t * 1024 + hoff + c4 * 4 + 2] = gv.z * acc[c4 * 4 + 2] * inv;
            P_out[rowbase + (size_t)t * 1024 + hoff + c4 * 4 + 3] = gv.w * acc[c4 * 4 + 3] * inv;
        }
    }
}

// ---------------- K4: out = gated[32768x256] @ Wf[256x128] + bf, x mask ----
__global__ __launch_bounds__(256) void k_out(const float* __restrict__ P,
                                             const float* __restrict__ Wf,
                                             const float* __restrict__ bf_,
                                             const float* __restrict__ mask,
                                             float* __restrict__ out)
{
    const int rb = blockIdx.x;       // 2048 blocks of 16 rows
    const int t = threadIdx.x;
    __shared__ float gs[16][HC];
    const int row0 = rb * 16;
#pragma unroll
    for (int e = 0; e < 16; ++e) {
        int idx = e * 256 + t;
        int r = idx >> 8, j = idx & 255;
        gs[r][j] = P[(size_t)(row0 + r) * 1024 + j];
    }
    __syncthreads();
    const int col = t & 127;
    const int rg  = t >> 7;          // 0 or 1 (8 rows each)
    float acc[8];
#pragma unroll
    for (int a = 0; a < 8; ++a) acc[a] = 0.0f;
    for (int j = 0; j < HC; ++j) {
        float w = Wf[(size_t)j * DD + col];
#pragma unroll
        for (int a = 0; a < 8; ++a) acc[a] += gs[rg * 8 + a][j] * w;
    }
    float bfv = bf_[col];
#pragma unroll
    for (int a = 0; a < 8; ++a) {
        int row = row0 + rg * 8 + a;
        out[(size_t)row * DD + col] = (acc[a] + bfv) * mask[row];
    }
}

extern "C" void kernel_launch(void* const* d_in, const int* in_sizes, int n_in,
                              void* d_out, int out_size, void* d_ws, size_t ws_size,
                              hipStream_t stream)
{
    const float* z     = (const float*)d_in[0];
    const float* djk   = (const float*)d_in[1];
    const float* mask  = (const float*)d_in[2];
    const float* gamma = (const float*)d_in[3];
    const float* beta  = (const float*)d_in[4];
    const float* Wq    = (const float*)d_in[5];
    const float* Wk    = (const float*)d_in[6];
    const float* Wv    = (const float*)d_in[7];
    // d_in[8] = Wb: per-query bias is constant along the softmax axis -> cancels exactly.
    const float* Wd    = (const float*)d_in[9];
    const float* Wg    = (const float*)d_in[10];
    const float* bg    = (const float*)d_in[11];
    const float* Wf    = (const float*)d_in[12];
    const float* bf_   = (const float*)d_in[13];
    float* out = (float*)d_out;

    float* zn = (float*)d_ws;                    // 32768*128 f32  (16.8 MB)
    float* P  = zn + (size_t)NROW * DD;          // 32768*1024 f32 (134 MB)

    k_ln  <<<NROW, 128, 0, stream>>>(z, gamma, beta, zn);
    k_proj<<<dim3(NROW / BM, 1024 / BN), 256, 0, stream>>>(zn, Wq, Wk, Wv, Wg, bg, P);
    k_attn<<<dim3(II, HH), 256, 0, stream>>>(P, P, djk, Wd, mask);
    k_out <<<NROW / 16, 256, 0, stream>>>(P, Wf, bf_, mask, out);
}

// Round 2
// 268.648 us; speedup vs baseline: 1.9666x; 1.9666x over previous
//
#include <hip/hip_runtime.h>
#include <hip/hip_bf16.h>
#include <math.h>

#define HH 8
#define CC 32
#define DD 128
#define HC 256
#define II 128
#define LL 256
#define NROW (II*LL)   // 32768
#define LN_EPS 1e-5f
#define BM 64
#define BN 64

typedef float f32x4 __attribute__((ext_vector_type(4)));
typedef short short8 __attribute__((ext_vector_type(8)));

static __device__ __forceinline__ unsigned short bfc(float x) {
    return __builtin_bit_cast(unsigned short, __float2bfloat16(x));
}

// ---------------- K1: LayerNorm over last dim (D=128), one block per row ----
__global__ __launch_bounds__(128) void k_ln(const float* __restrict__ z,
                                            const float* __restrict__ gamma,
                                            const float* __restrict__ beta,
                                            float* __restrict__ zn)
{
    const int row = blockIdx.x;
    const int t = threadIdx.x;
    __shared__ float red[128];
    float x = z[(size_t)row * DD + t];
    red[t] = x;
    __syncthreads();
    for (int s = 64; s > 0; s >>= 1) {
        if (t < s) red[t] += red[t + s];
        __syncthreads();
    }
    float mu = red[0] * (1.0f / DD);
    __syncthreads();
    float d = x - mu;
    red[t] = d * d;
    __syncthreads();
    for (int s = 64; s > 0; s >>= 1) {
        if (t < s) red[t] += red[t + s];
        __syncthreads();
    }
    float rstd = rsqrtf(red[0] * (1.0f / DD) + LN_EPS);
    zn[(size_t)row * DD + t] = d * rstd * gamma[t] + beta[t];
}

// ---------------- K2: projections GEMM: zn[32768x128] @ W[128x1024] --------
__global__ __launch_bounds__(256) void k_proj(const float* __restrict__ zn,
                                              const float* __restrict__ Wq,
                                              const float* __restrict__ Wk,
                                              const float* __restrict__ Wv,
                                              const float* __restrict__ Wg,
                                              const float* __restrict__ bg,
                                              float* __restrict__ P)
{
    const int rb = blockIdx.x;
    const int cb = blockIdx.y;
    const int t  = threadIdx.x;
    __shared__ float As[DD][BM + 1];
    __shared__ float Bs[DD][BN];
    const int row0 = rb * BM;
    const int colg = cb * BN;
    const int mat  = colg >> 8;
    const int lc0  = colg & 255;
    const float* W = (mat == 0) ? Wq : (mat == 1) ? Wk : (mat == 2) ? Wv : Wg;

#pragma unroll
    for (int e = 0; e < 32; ++e) {
        int idx = e * 256 + t;
        int m = idx >> 7, k = idx & 127;
        As[k][m] = zn[(size_t)(row0 + m) * DD + k];
    }
#pragma unroll
    for (int e = 0; e < 32; ++e) {
        int idx = e * 256 + t;
        int k = idx >> 6, n = idx & 63;
        Bs[k][n] = W[(size_t)k * HC + lc0 + n];
    }
    __syncthreads();

    const int tx = t & 15, ty = t >> 4;
    float acc[4][4];
#pragma unroll
    for (int a = 0; a < 4; ++a)
#pragma unroll
        for (int b = 0; b < 4; ++b) acc[a][b] = 0.0f;

    for (int k = 0; k < DD; ++k) {
        float4 av = *(const float4*)&As[k][ty * 4];
        float4 bv = *(const float4*)&Bs[k][tx * 4];
        float aa[4] = {av.x, av.y, av.z, av.w};
        float bb[4] = {bv.x, bv.y, bv.z, bv.w};
#pragma unroll
        for (int a = 0; a < 4; ++a)
#pragma unroll
            for (int b = 0; b < 4; ++b) acc[a][b] += aa[a] * bb[b];
    }

#pragma unroll
    for (int a = 0; a < 4; ++a) {
        int row = row0 + ty * 4 + a;
#pragma unroll
        for (int b = 0; b < 4; ++b) {
            int lc = lc0 + tx * 4 + b;
            float v = acc[a][b];
            if (mat == 0) v *= 0.35355339059327373f;
            else if (mat == 3) v = 1.0f / (1.0f + __expf(-(v + bg[lc])));
            P[(size_t)row * 1024 + (mat << 8) + lc] = v;
        }
    }
}

// ---------------- K3: MFMA attention per (i,h) ------------------------------
// P row layout: [0:256)=q(scaled) [256:512)=k [512:768)=v [768:1024)=g
// Computes S^T = K·Q^T per tile (D: row=k=4g+r, col=q=l0), adds wd*d+madd,
// exp (no max subtraction: logits bounded, softmax shift-invariant),
// packs P^T frags in-register, O^T = V^T·P^T, gates, writes q-slot in place.
__global__ __launch_bounds__(256) void k_attn(float* __restrict__ P,
                                              const float* __restrict__ djk,
                                              const float* __restrict__ Wd,
                                              const float* __restrict__ mask)
{
    const int i = blockIdx.x;
    const int h = blockIdx.y;
    const int t = threadIdx.x;
    const size_t rowbase = (size_t)i * LL * 1024;
    const int hoff = h * CC;

    __shared__ unsigned short ks[LL][36];   // K bf16, padded stride
    __shared__ unsigned short vt[CC][260];  // V^T bf16, padded stride
    __shared__ float madd[LL];

    // ---- stage K and V^T (all 256 threads) ----
    {
        const int cp = t & 15;          // column pair: c = 2cp
        const int kb = t >> 4;          // base k row
#pragma unroll
        for (int e = 0; e < 16; ++e) {
            int k = kb + 16 * e;
            const float* src = P + rowbase + (size_t)k * 1024 + hoff;
            float2 kv = *(const float2*)(src + 256 + 2 * cp);
            float2 vv = *(const float2*)(src + 512 + 2 * cp);
            unsigned int kp = (unsigned int)bfc(kv.x) | ((unsigned int)bfc(kv.y) << 16);
            ((unsigned int*)&ks[k][0])[cp] = kp;
            vt[2 * cp + 0][k] = bfc(vv.x);
            vt[2 * cp + 1][k] = bfc(vv.y);
        }
        madd[t] = 1e9f * (mask[i * LL + t] - 1.0f);
    }

    const int lane = t & 63;
    const int w    = t >> 6;
    const int l0   = lane & 15;
    const int g    = lane >> 4;
    const int q0   = w * 64;
    const float wd = Wd[h];

    // ---- load Q^T fragments (B-operand: col=q=l0, k-dim=d=4g+(j&3)+16*(j>>2))
    short8 qf[4];
    const float* djk_q[4];
    int qrow[4];
#pragma unroll
    for (int qt = 0; qt < 4; ++qt) {
        qrow[qt] = q0 + qt * 16 + l0;
        djk_q[qt] = djk + (size_t)qrow[qt] * LL;
        const float* base = P + rowbase + (size_t)qrow[qt] * 1024 + hoff;
        f32x4 a = *(const f32x4*)(base + 4 * g);
        f32x4 b = *(const f32x4*)(base + 16 + 4 * g);
        qf[qt][0] = (short)bfc(a.x); qf[qt][1] = (short)bfc(a.y);
        qf[qt][2] = (short)bfc(a.z); qf[qt][3] = (short)bfc(a.w);
        qf[qt][4] = (short)bfc(b.x); qf[qt][5] = (short)bfc(b.y);
        qf[qt][6] = (short)bfc(b.z); qf[qt][7] = (short)bfc(b.w);
    }
    __syncthreads();

    f32x4 oacc[2][4];
#pragma unroll
    for (int ct = 0; ct < 2; ++ct)
#pragma unroll
        for (int qt = 0; qt < 4; ++qt) oacc[ct][qt] = (f32x4){0,0,0,0};
    float ssum[4] = {0, 0, 0, 0};

    for (int p = 0; p < 8; ++p) {
        unsigned short pf[4][2][4];   // [qt][half][r] bf16 P^T values
#pragma unroll
        for (int half = 0; half < 2; ++half) {
            const int kt = 2 * p + half;
            const int krow = kt * 16 + l0;
            // A-operand K fragment: row=k=l0, d = 4g+(j&3)+16*(j>>2)
            const unsigned short* kr = &ks[krow][4 * g];
            short8 kf;
#pragma unroll
            for (int j = 0; j < 4; ++j) { kf[j] = (short)kr[j]; kf[j + 4] = (short)kr[j + 16]; }
            const float* mv = &madd[kt * 16 + 4 * g];
            f32x4 mvv = *(const f32x4*)mv;
#pragma unroll
            for (int qt = 0; qt < 4; ++qt) {
                f32x4 z = {0, 0, 0, 0};
                f32x4 s = __builtin_amdgcn_mfma_f32_16x16x32_bf16(kf, qf[qt], z, 0, 0, 0);
                f32x4 dv = *(const f32x4*)(djk_q[qt] + kt * 16 + 4 * g);
                float p0 = __expf(s[0] + wd * dv.x + mvv.x);
                float p1 = __expf(s[1] + wd * dv.y + mvv.y);
                float p2 = __expf(s[2] + wd * dv.z + mvv.z);
                float p3 = __expf(s[3] + wd * dv.w + mvv.w);
                ssum[qt] += (p0 + p1) + (p2 + p3);
                pf[qt][half][0] = bfc(p0); pf[qt][half][1] = bfc(p1);
                pf[qt][half][2] = bfc(p2); pf[qt][half][3] = bfc(p3);
            }
        }
        // PV: O^T = V^T · P^T over k-chunk [32p, 32p+32)
#pragma unroll
        for (int ct = 0; ct < 2; ++ct) {
            const unsigned short* vr = &vt[ct * 16 + l0][32 * p + 4 * g];
            short8 vf;
#pragma unroll
            for (int j = 0; j < 4; ++j) { vf[j] = (short)vr[j]; vf[j + 4] = (short)vr[j + 16]; }
#pragma unroll
            for (int qt = 0; qt < 4; ++qt) {
                short8 pfr;
#pragma unroll
                for (int j = 0; j < 4; ++j) {
                    pfr[j]     = (short)pf[qt][0][j];
                    pfr[j + 4] = (short)pf[qt][1][j];
                }
                oacc[ct][qt] = __builtin_amdgcn_mfma_f32_16x16x32_bf16(vf, pfr, oacc[ct][qt], 0, 0, 0);
            }
        }
    }

    // ---- epilogue: row sums, gate, write in place into q slot ----
#pragma unroll
    for (int qt = 0; qt < 4; ++qt) {
        float s = ssum[qt];
        s += __shfl_xor(s, 16, 64);
        s += __shfl_xor(s, 32, 64);
        float inv = 1.0f / s;
        float* base = P + rowbase + (size_t)qrow[qt] * 1024 + hoff;
#pragma unroll
        for (int ct = 0; ct < 2; ++ct) {
            f32x4 gv = *(const f32x4*)(base + 768 + ct * 16 + 4 * g);
            f32x4 ov = oacc[ct][qt];
            f32x4 res;
            res.x = gv.x * ov.x * inv;
            res.y = gv.y * ov.y * inv;
            res.z = gv.z * ov.z * inv;
            res.w = gv.w * ov.w * inv;
            *(f32x4*)(base + ct * 16 + 4 * g) = res;
        }
    }
}

// ---------------- K4: out = gated[32768x256] @ Wf[256x128] + bf, x mask ----
__global__ __launch_bounds__(256) void k_out(const float* __restrict__ P,
                                             const float* __restrict__ Wf,
                                             const float* __restrict__ bf_,
                                             const float* __restrict__ mask,
                                             float* __restrict__ out)
{
    const int rb = blockIdx.x;
    const int t = threadIdx.x;
    __shared__ float gs[16][HC];
    const int row0 = rb * 16;
#pragma unroll
    for (int e = 0; e < 16; ++e) {
        int idx = e * 256 + t;
        int r = idx >> 8, j = idx & 255;
        gs[r][j] = P[(size_t)(row0 + r) * 1024 + j];
    }
    __syncthreads();
    const int col = t & 127;
    const int rg  = t >> 7;
    float acc[8];
#pragma unroll
    for (int a = 0; a < 8; ++a) acc[a] = 0.0f;
    for (int j = 0; j < HC; ++j) {
        float w = Wf[(size_t)j * DD + col];
#pragma unroll
        for (int a = 0; a < 8; ++a) acc[a] += gs[rg * 8 + a][j] * w;
    }
    float bfv = bf_[col];
#pragma unroll
    for (int a = 0; a < 8; ++a) {
        int row = row0 + rg * 8 + a;
        out[(size_t)row * DD + col] = (acc[a] + bfv) * mask[row];
    }
}

extern "C" void kernel_launch(void* const* d_in, const int* in_sizes, int n_in,
                              void* d_out, int out_size, void* d_ws, size_t ws_size,
                              hipStream_t stream)
{
    const float* z     = (const float*)d_in[0];
    const float* djk   = (const float*)d_in[1];
    const float* mask  = (const float*)d_in[2];
    const float* gamma = (const float*)d_in[3];
    const float* beta  = (const float*)d_in[4];
    const float* Wq    = (const float*)d_in[5];
    const float* Wk    = (const float*)d_in[6];
    const float* Wv    = (const float*)d_in[7];
    // d_in[8] = Wb: constant along softmax axis -> cancels exactly.
    const float* Wd    = (const float*)d_in[9];
    const float* Wg    = (const float*)d_in[10];
    const float* bg    = (const float*)d_in[11];
    const float* Wf    = (const float*)d_in[12];
    const float* bf_   = (const float*)d_in[13];
    float* out = (float*)d_out;

    float* zn = (float*)d_ws;
    float* P  = zn + (size_t)NROW * DD;

    k_ln  <<<NROW, 128, 0, stream>>>(z, gamma, beta, zn);
    k_proj<<<dim3(NROW / BM, 1024 / BN), 256, 0, stream>>>(zn, Wq, Wk, Wv, Wg, bg, P);
    k_attn<<<dim3(II, HH), 256, 0, stream>>>(P, djk, Wd, mask);
    k_out <<<NROW / 16, 256, 0, stream>>>(P, Wf, bf_, mask, out);
}

// Round 3
// 111.320 us; speedup vs baseline: 4.7459x; 2.4133x over previous
//
#include <hip/hip_runtime.h>
#include <hip/hip_bf16.h>
#include <math.h>

#define HH 8
#define CC 32
#define DD 128
#define HC 256
#define II 128
#define LL 256
#define NROW (II*LL)   // 32768
#define LN_EPS 1e-5f

typedef float f32x4 __attribute__((ext_vector_type(4)));
typedef short short8 __attribute__((ext_vector_type(8)));
typedef short short4v __attribute__((ext_vector_type(4)));
typedef unsigned short us;

static __device__ __forceinline__ us bfc(float x) {
    return __builtin_bit_cast(us, __float2bfloat16(x));
}
static __device__ __forceinline__ float bf2f(us h) {
    return __builtin_bit_cast(float, ((unsigned int)h) << 16);
}

// ---------------- K1: LayerNorm, 1 wave per row, bf16 out -------------------
__global__ __launch_bounds__(256) void k_ln(const float* __restrict__ z,
                                            const float* __restrict__ gamma,
                                            const float* __restrict__ beta,
                                            us* __restrict__ zn)
{
    const int t = threadIdx.x;
    const int row = blockIdx.x * 4 + (t >> 6);
    const int lane = t & 63;
    float2 x = *(const float2*)(z + (size_t)row * DD + lane * 2);
    float s = x.x + x.y;
    float s2 = x.x * x.x + x.y * x.y;
#pragma unroll
    for (int off = 1; off < 64; off <<= 1) {
        s  += __shfl_xor(s, off, 64);
        s2 += __shfl_xor(s2, off, 64);
    }
    float mu = s * (1.0f / DD);
    float var = s2 * (1.0f / DD) - mu * mu;
    float rstd = rsqrtf(var + LN_EPS);
    float2 gm = *(const float2*)(gamma + lane * 2);
    float2 bt = *(const float2*)(beta + lane * 2);
    float y0 = (x.x - mu) * rstd * gm.x + bt.x;
    float y1 = (x.y - mu) * rstd * gm.y + bt.y;
    unsigned int pk = (unsigned int)bfc(y0) | ((unsigned int)bfc(y1) << 16);
    ((unsigned int*)zn)[(size_t)row * 64 + lane] = pk;
}

// ---------------- K1b: split Wf into hi/lo bf16, MFMA B-frag packed ---------
// Frag layout: [ks(8)][nf(8)][lane(64)][slot(8)], k = ks*32+4g+(slot&3)+16*(slot>>2)
__global__ __launch_bounds__(256) void k_wprep(const float* __restrict__ Wf,
                                               us* __restrict__ WfpH,
                                               us* __restrict__ WfpL)
{
    int idx = (blockIdx.x * 256 + threadIdx.x) * 4;
#pragma unroll
    for (int e = 0; e < 4; ++e, ++idx) {
        int k = idx >> 7, n = idx & 127;
        float w = Wf[idx];
        us hi = bfc(w);
        us lo = bfc(w - bf2f(hi));
        int kk = k & 31;
        int g = (kk & 15) >> 2, b = kk >> 4, j0 = kk & 3;
        int lane = (n & 15) | (g << 4);
        size_t dst = ((size_t)((k >> 5) * 8 + (n >> 4)) * 64 + lane) * 8 + b * 4 + j0;
        WfpH[dst] = hi;
        WfpL[dst] = lo;
    }
}

// ---------------- K2: projections via bf16 MFMA -----------------------------
// C[32768x1024] = zn[32768x128] @ [Wq|Wk|Wv|Wg]; P bf16 row layout:
// [0:256)=q(scaled) [256:512)=k [512:768)=v [768:1024)=g (sigmoid)
// LDS: permuted-k layout so each MFMA fragment is one ds_read_b128.
// perm(kk) = 8*((kk&15)>>2) + 4*(kk>>4) + (kk&3)
__global__ __launch_bounds__(256) void k_proj(const us* __restrict__ zn,
                                              const float* __restrict__ Wq,
                                              const float* __restrict__ Wk,
                                              const float* __restrict__ Wv,
                                              const float* __restrict__ Wg,
                                              const float* __restrict__ bg,
                                              us* __restrict__ P)
{
    const int rb = blockIdx.x, cb = blockIdx.y, t = threadIdx.x;
    const int m0 = rb * 128, n0 = cb * 128;
    const int mat = n0 >> 8, lc0 = n0 & 255;
    const float* W = (mat == 0) ? Wq : (mat == 1) ? Wk : (mat == 2) ? Wv : Wg;
    __shared__ us A[128][136];   // 272B rows: 16B-aligned, 2-way banks (free)
    __shared__ us B[128][136];   // B transposed: [n][k-perm]

    // A stage: 16B global chunk (8 k) -> two 8B halves at perm positions
#pragma unroll
    for (int e = 0; e < 8; ++e) {
        int cid = e * 256 + t;
        int row = cid >> 4, c = cid & 15;
        uint4 q = *(const uint4*)(zn + (size_t)(m0 + row) * DD + c * 8);
        int ks = c >> 2, cc = c & 3;
        int fe = (cc & 1) * 16 + (cc >> 1) * 4;
        *(uint2*)&A[row][ks * 32 + fe]     = make_uint2(q.x, q.y);
        *(uint2*)&A[row][ks * 32 + fe + 8] = make_uint2(q.z, q.w);
    }
    // B stage: read W[k][n] f32 coalesced, cvt, transposed scalar writes
    {
        int k = t >> 1, nh = (t & 1) * 64;
        int kk = k & 31;
        int col = (k >> 5) * 32 + 8 * ((kk & 15) >> 2) + 4 * (kk >> 4) + (kk & 3);
#pragma unroll
        for (int i = 0; i < 16; ++i) {
            int n = nh + i * 4;
            float4 wv = *(const float4*)(W + (size_t)k * HC + lc0 + n);
            B[n + 0][col] = bfc(wv.x);
            B[n + 1][col] = bfc(wv.y);
            B[n + 2][col] = bfc(wv.z);
            B[n + 3][col] = bfc(wv.w);
        }
    }
    __syncthreads();

    const int lane = t & 63, w = t >> 6;
    const int wm = w & 1, wn = w >> 1;
    const int l0 = lane & 15, g = lane >> 4;
    f32x4 acc[4][4];
#pragma unroll
    for (int a = 0; a < 4; ++a)
#pragma unroll
        for (int b = 0; b < 4; ++b) acc[a][b] = (f32x4){0, 0, 0, 0};

#pragma unroll
    for (int ks = 0; ks < 4; ++ks) {
        short8 af[4], bfr[4];
#pragma unroll
        for (int mf = 0; mf < 4; ++mf)
            af[mf] = *(const short8*)&A[wm * 64 + mf * 16 + l0][ks * 32 + 8 * g];
#pragma unroll
        for (int nf = 0; nf < 4; ++nf)
            bfr[nf] = *(const short8*)&B[wn * 64 + nf * 16 + l0][ks * 32 + 8 * g];
#pragma unroll
        for (int mf = 0; mf < 4; ++mf)
#pragma unroll
            for (int nf = 0; nf < 4; ++nf)
                acc[mf][nf] = __builtin_amdgcn_mfma_f32_16x16x32_bf16(af[mf], bfr[nf], acc[mf][nf], 0, 0, 0);
    }

    // epilogue: D row = 4g+r (+tile), col = l0 (+tile)
#pragma unroll
    for (int nf = 0; nf < 4; ++nf) {
        int lc = lc0 + wn * 64 + nf * 16 + l0;
        float bgv = (mat == 3) ? bg[lc] : 0.0f;
#pragma unroll
        for (int mf = 0; mf < 4; ++mf) {
#pragma unroll
            for (int r = 0; r < 4; ++r) {
                int rowm = m0 + wm * 64 + mf * 16 + 4 * g + r;
                float v = acc[mf][nf][r];
                if (mat == 0) v *= 0.35355339059327373f;
                else if (mat == 3) v = 1.0f / (1.0f + __expf(-(v + bgv)));
                P[(size_t)rowm * 1024 + mat * 256 + lc] = bfc(v);
            }
        }
    }
}

// ---------------- K3: MFMA attention per (i,h), bf16 P ----------------------
__global__ __launch_bounds__(256) void k_attn(us* __restrict__ P,
                                              const float* __restrict__ djk,
                                              const float* __restrict__ Wd,
                                              const float* __restrict__ mask)
{
    const int i = blockIdx.x, h = blockIdx.y, t = threadIdx.x;
    const size_t rowbase = (size_t)i * LL * 1024;
    const int hoff = h * CC;
    __shared__ us ksl[LL][40];    // K, perm-d, 80B rows
    __shared__ us vt[CC][264];    // V^T, perm-k per 32-block, 528B rows
    __shared__ float madd[LL];

    // K stage: 16B chunks -> perm positions (d-dim perm within the 32 cols)
#pragma unroll
    for (int e = 0; e < 4; ++e) {
        int cid = e * 256 + t;
        int row = cid >> 2, c = cid & 3;
        uint4 q = *(const uint4*)(P + rowbase + (size_t)row * 1024 + 256 + hoff + c * 8);
        int fe = (c & 1) * 16 + (c >> 1) * 4;
        *(uint2*)&ksl[row][fe]     = make_uint2(q.x, q.y);
        *(uint2*)&ksl[row][fe + 8] = make_uint2(q.z, q.w);
    }
    // V^T stage: scalar transpose into perm-k positions
#pragma unroll
    for (int e = 0; e < 4; ++e) {
        int cid = e * 256 + t;
        int r = cid >> 2, c = cid & 3;
        short8 vv = *(const short8*)(P + rowbase + (size_t)r * 1024 + 512 + hoff + c * 8);
        int kk = r & 31;
        int pos = (r >> 5) * 32 + 8 * ((kk & 15) >> 2) + 4 * (kk >> 4) + (kk & 3);
#pragma unroll
        for (int u = 0; u < 8; ++u)
            vt[c * 8 + u][pos] = (us)vv[u];
    }
    madd[t] = 1e9f * (mask[i * LL + t] - 1.0f);

    const int lane = t & 63, w = t >> 6;
    const int l0 = lane & 15, g = lane >> 4;
    const int q0 = w * 64;
    const float wd = Wd[h];

    short8 qf[4];
    const float* djk_q[4];
    int qrow[4];
#pragma unroll
    for (int qt = 0; qt < 4; ++qt) {
        qrow[qt] = q0 + qt * 16 + l0;
        djk_q[qt] = djk + (size_t)qrow[qt] * LL;
        const us* qb = P + rowbase + (size_t)qrow[qt] * 1024 + hoff;
        short4v a = *(const short4v*)(qb + 4 * g);
        short4v b = *(const short4v*)(qb + 16 + 4 * g);
        qf[qt][0] = a.x; qf[qt][1] = a.y; qf[qt][2] = a.z; qf[qt][3] = a.w;
        qf[qt][4] = b.x; qf[qt][5] = b.y; qf[qt][6] = b.z; qf[qt][7] = b.w;
    }
    __syncthreads();

    f32x4 oacc[2][4];
#pragma unroll
    for (int ct = 0; ct < 2; ++ct)
#pragma unroll
        for (int qt = 0; qt < 4; ++qt) oacc[ct][qt] = (f32x4){0, 0, 0, 0};
    float ssum[4] = {0, 0, 0, 0};

    for (int p = 0; p < 8; ++p) {
        us pf[4][2][4];
#pragma unroll
        for (int half = 0; half < 2; ++half) {
            const int kt = 2 * p + half;
            const int krow = kt * 16 + l0;
            short8 kf = *(const short8*)&ksl[krow][8 * g];
            f32x4 mvv = *(const f32x4*)&madd[kt * 16 + 4 * g];
#pragma unroll
            for (int qt = 0; qt < 4; ++qt) {
                f32x4 z4 = {0, 0, 0, 0};
                f32x4 s = __builtin_amdgcn_mfma_f32_16x16x32_bf16(kf, qf[qt], z4, 0, 0, 0);
                f32x4 dv = *(const f32x4*)(djk_q[qt] + kt * 16 + 4 * g);
                float p0 = __expf(s[0] + wd * dv.x + mvv.x);
                float p1 = __expf(s[1] + wd * dv.y + mvv.y);
                float p2 = __expf(s[2] + wd * dv.z + mvv.z);
                float p3 = __expf(s[3] + wd * dv.w + mvv.w);
                ssum[qt] += (p0 + p1) + (p2 + p3);
                pf[qt][half][0] = bfc(p0); pf[qt][half][1] = bfc(p1);
                pf[qt][half][2] = bfc(p2); pf[qt][half][3] = bfc(p3);
            }
        }
#pragma unroll
        for (int ct = 0; ct < 2; ++ct) {
            short8 vf = *(const short8*)&vt[ct * 16 + l0][32 * p + 8 * g];
#pragma unroll
            for (int qt = 0; qt < 4; ++qt) {
                short8 pfr;
#pragma unroll
                for (int j = 0; j < 4; ++j) {
                    pfr[j]     = (short)pf[qt][0][j];
                    pfr[j + 4] = (short)pf[qt][1][j];
                }
                oacc[ct][qt] = __builtin_amdgcn_mfma_f32_16x16x32_bf16(vf, pfr, oacc[ct][qt], 0, 0, 0);
            }
        }
    }

#pragma unroll
    for (int qt = 0; qt < 4; ++qt) {
        float s = ssum[qt];
        s += __shfl_xor(s, 16, 64);
        s += __shfl_xor(s, 32, 64);
        float inv = 1.0f / s;
        us* base = P + rowbase + (size_t)qrow[qt] * 1024 + hoff;
#pragma unroll
        for (int ct = 0; ct < 2; ++ct) {
            short4v gv = *(const short4v*)(base + 768 + ct * 16 + 4 * g);
            f32x4 ov = oacc[ct][qt];
            short4v res;
            res.x = (short)bfc(bf2f((us)gv.x) * ov.x * inv);
            res.y = (short)bfc(bf2f((us)gv.y) * ov.y * inv);
            res.z = (short)bfc(bf2f((us)gv.z) * ov.z * inv);
            res.w = (short)bfc(bf2f((us)gv.w) * ov.w * inv);
            *(short4v*)(base + ct * 16 + 4 * g) = res;
        }
    }
}

// ---------------- K4: out = gated @ (WfH + WfL) + bf, x mask (MFMA) ---------
__global__ __launch_bounds__(256) void k_out(const us* __restrict__ P,
                                             const us* __restrict__ WfpH,
                                             const us* __restrict__ WfpL,
                                             const float* __restrict__ bf_,
                                             const float* __restrict__ mask,
                                             float* __restrict__ out)
{
    const int t = threadIdx.x;
    const int m0 = blockIdx.x * 64;
    __shared__ us A[64][264];
#pragma unroll
    for (int e = 0; e < 8; ++e) {
        int cid = e * 256 + t;
        int row = cid >> 5, c = cid & 31;
        uint4 q = *(const uint4*)(P + (size_t)(m0 + row) * 1024 + c * 8);
        int ksb = c >> 2, cc = c & 3;
        int fe = (cc & 1) * 16 + (cc >> 1) * 4;
        *(uint2*)&A[row][ksb * 32 + fe]     = make_uint2(q.x, q.y);
        *(uint2*)&A[row][ksb * 32 + fe + 8] = make_uint2(q.z, q.w);
    }
    __syncthreads();
    const int lane = t & 63, w = t >> 6;
    const int l0 = lane & 15, g = lane >> 4;
    f32x4 acc[8];
#pragma unroll
    for (int nf = 0; nf < 8; ++nf) acc[nf] = (f32x4){0, 0, 0, 0};

#pragma unroll
    for (int ksb = 0; ksb < 8; ++ksb) {
        short8 af = *(const short8*)&A[w * 16 + l0][ksb * 32 + 8 * g];
#pragma unroll
        for (int nf = 0; nf < 8; ++nf) {
            short8 bh = *(const short8*)(WfpH + ((size_t)(ksb * 8 + nf) * 64 + lane) * 8);
            short8 bl = *(const short8*)(WfpL + ((size_t)(ksb * 8 + nf) * 64 + lane) * 8);
            acc[nf] = __builtin_amdgcn_mfma_f32_16x16x32_bf16(af, bh, acc[nf], 0, 0, 0);
            acc[nf] = __builtin_amdgcn_mfma_f32_16x16x32_bf16(af, bl, acc[nf], 0, 0, 0);
        }
    }
    float maskv[4];
    int rowm[4];
#pragma unroll
    for (int r = 0; r < 4; ++r) {
        rowm[r] = m0 + w * 16 + 4 * g + r;
        maskv[r] = mask[rowm[r]];
    }
#pragma unroll
    for (int nf = 0; nf < 8; ++nf) {
        int n = nf * 16 + l0;
        float bfv = bf_[n];
#pragma unroll
        for (int r = 0; r < 4; ++r)
            out[(size_t)rowm[r] * DD + n] = (acc[nf][r] + bfv) * maskv[r];
    }
}

extern "C" void kernel_launch(void* const* d_in, const int* in_sizes, int n_in,
                              void* d_out, int out_size, void* d_ws, size_t ws_size,
                              hipStream_t stream)
{
    const float* z     = (const float*)d_in[0];
    const float* djk   = (const float*)d_in[1];
    const float* mask  = (const float*)d_in[2];
    const float* gamma = (const float*)d_in[3];
    const float* beta  = (const float*)d_in[4];
    const float* Wq    = (const float*)d_in[5];
    const float* Wk    = (const float*)d_in[6];
    const float* Wv    = (const float*)d_in[7];
    // d_in[8] = Wb: constant along softmax axis -> cancels exactly.
    const float* Wd    = (const float*)d_in[9];
    const float* Wg    = (const float*)d_in[10];
    const float* bg    = (const float*)d_in[11];
    const float* Wf    = (const float*)d_in[12];
    const float* bf_   = (const float*)d_in[13];
    float* out = (float*)d_out;

    us* zn   = (us*)d_ws;                        // 32768*128  bf16 (8.4 MB)
    us* P    = zn + (size_t)NROW * DD;           // 32768*1024 bf16 (67 MB)
    us* WfpH = P + (size_t)NROW * 1024;          // 64 KB
    us* WfpL = WfpH + 256 * 128;                 // 64 KB

    k_ln   <<<NROW / 4, 256, 0, stream>>>(z, gamma, beta, zn);
    k_wprep<<<32, 256, 0, stream>>>(Wf, WfpH, WfpL);
    k_proj <<<dim3(NROW / 128, 8), 256, 0, stream>>>(zn, Wq, Wk, Wv, Wg, bg, P);
    k_attn <<<dim3(II, HH), 256, 0, stream>>>(P, djk, Wd, mask);
    k_out  <<<NROW / 64, 256, 0, stream>>>(P, WfpH, WfpL, bf_, mask, out);
}

// Round 4
// 107.279 us; speedup vs baseline: 4.9247x; 1.0377x over previous
//
#include <hip/hip_runtime.h>
#include <hip/hip_bf16.h>
#include <math.h>

#define HH 8
#define CC 32
#define DD 128
#define HC 256
#define II 128
#define LL 256
#define NROW (II*LL)   // 32768
#define LN_EPS 1e-5f

typedef float f32x4 __attribute__((ext_vector_type(4)));
typedef short short8 __attribute__((ext_vector_type(8)));
typedef short short4v __attribute__((ext_vector_type(4)));
typedef unsigned short us;

static __device__ __forceinline__ us bfc(float x) {
    return __builtin_bit_cast(us, __float2bfloat16(x));
}
static __device__ __forceinline__ float bf2f(us h) {
    return __builtin_bit_cast(float, ((unsigned int)h) << 16);
}

// ---------------- K1: LayerNorm, 1 wave per row, bf16 out -------------------
__global__ __launch_bounds__(256) void k_ln(const float* __restrict__ z,
                                            const float* __restrict__ gamma,
                                            const float* __restrict__ beta,
                                            us* __restrict__ zn)
{
    const int t = threadIdx.x;
    const int row = blockIdx.x * 4 + (t >> 6);
    const int lane = t & 63;
    float2 x = *(const float2*)(z + (size_t)row * DD + lane * 2);
    float s = x.x + x.y;
    float s2 = x.x * x.x + x.y * x.y;
#pragma unroll
    for (int off = 1; off < 64; off <<= 1) {
        s  += __shfl_xor(s, off, 64);
        s2 += __shfl_xor(s2, off, 64);
    }
    float mu = s * (1.0f / DD);
    float var = s2 * (1.0f / DD) - mu * mu;
    float rstd = rsqrtf(var + LN_EPS);
    float2 gm = *(const float2*)(gamma + lane * 2);
    float2 bt = *(const float2*)(beta + lane * 2);
    float y0 = (x.x - mu) * rstd * gm.x + bt.x;
    float y1 = (x.y - mu) * rstd * gm.y + bt.y;
    unsigned int pk = (unsigned int)bfc(y0) | ((unsigned int)bfc(y1) << 16);
    ((unsigned int*)zn)[(size_t)row * 64 + lane] = pk;
}

// ---------------- K1b: weight prep ------------------------------------------
// blocks 0..127: Wq(*scale)/Wk/Wv/Wg -> B-frag bf16 layout F[mat][ks][nfg][lane][8]
//   k = ks*32 + 4g + (slot&3) + 16*(slot>>2), lane = (n&15)|(g<<4)
// blocks 128..159: Wf -> hi/lo split frags (f32-grade final GEMM)
__global__ __launch_bounds__(256) void k_wprep(const float* __restrict__ Wq,
                                               const float* __restrict__ Wk,
                                               const float* __restrict__ Wv,
                                               const float* __restrict__ Wg,
                                               const float* __restrict__ Wf,
                                               us* __restrict__ F,
                                               us* __restrict__ WfpH,
                                               us* __restrict__ WfpL)
{
    const int bid = blockIdx.x;
    if (bid < 128) {
        const int mat = bid >> 5;
        const float* W = (mat == 0) ? Wq : (mat == 1) ? Wk : (mat == 2) ? Wv : Wg;
        const float scale = (mat == 0) ? 0.35355339059327373f : 1.0f;
        int base = (bid & 31) * 1024 + threadIdx.x * 4;   // [0, 32768)
        float4 wv = *(const float4*)(W + base);
        int k = base >> 8, n0 = base & 255;
        int ks = k >> 5, kk = k & 31;
        int slot = ((kk >> 4) << 2) | (kk & 3);
        int gg = (kk >> 2) & 3;
        float vals[4] = {wv.x, wv.y, wv.z, wv.w};
        us* Fb = F + mat * 32768;
#pragma unroll
        for (int e = 0; e < 4; ++e) {
            int n = n0 + e;
            int lane = (n & 15) | (gg << 4);
            Fb[((size_t)(ks * 16 + (n >> 4)) * 64 + lane) * 8 + slot] = bfc(vals[e] * scale);
        }
    } else {
        int idx = ((bid - 128) * 256 + threadIdx.x) * 4;
#pragma unroll
        for (int e = 0; e < 4; ++e, ++idx) {
            int k = idx >> 7, n = idx & 127;
            float w = Wf[idx];
            us hi = bfc(w);
            us lo = bfc(w - bf2f(hi));
            int kk = k & 31;
            int g = (kk >> 2) & 3, b = kk >> 4, j0 = kk & 3;
            int lane = (n & 15) | (g << 4);
            size_t dst = ((size_t)((k >> 5) * 8 + (n >> 4)) * 64 + lane) * 8 + b * 4 + j0;
            WfpH[dst] = hi;
            WfpL[dst] = lo;
        }
    }
}

// ---------------- K2: projections via bf16 MFMA, frag weights from L2 -------
// P bf16 row layout: [0:256)=q(scaled) [256:512)=k [512:768)=v [768:1024)=g
__global__ __launch_bounds__(256, 4) void k_proj(const us* __restrict__ zn,
                                                 const us* __restrict__ F,
                                                 const float* __restrict__ bg,
                                                 us* __restrict__ P)
{
    const int rb = blockIdx.x, cb = blockIdx.y, t = threadIdx.x;
    const int m0 = rb * 128, n0 = cb * 128;
    const int mat = n0 >> 8, lc0 = n0 & 255;
    __shared__ us A[128][136];   // perm-k A tile; reused as C-stage

    // A stage: 16B chunks -> perm positions
#pragma unroll
    for (int e = 0; e < 8; ++e) {
        int cid = e * 256 + t;
        int row = cid >> 4, c = cid & 15;
        uint4 q = *(const uint4*)(zn + (size_t)(m0 + row) * DD + c * 8);
        int ks = c >> 2, cc = c & 3;
        int fe = (cc & 1) * 16 + (cc >> 1) * 4;
        *(uint2*)&A[row][ks * 32 + fe]     = make_uint2(q.x, q.y);
        *(uint2*)&A[row][ks * 32 + fe + 8] = make_uint2(q.z, q.w);
    }
    __syncthreads();

    const int lane = t & 63, w = t >> 6;
    const int wm = w & 1, wn = w >> 1;
    const int l0 = lane & 15, g = lane >> 4;
    const us* Fb = F + mat * 32768 + ((size_t)((lc0 >> 4) + wn * 4) * 64 + lane) * 8;
    f32x4 acc[4][4];
#pragma unroll
    for (int a = 0; a < 4; ++a)
#pragma unroll
        for (int b = 0; b < 4; ++b) acc[a][b] = (f32x4){0, 0, 0, 0};

#pragma unroll
    for (int ks = 0; ks < 4; ++ks) {
        short8 af[4], bfr[4];
#pragma unroll
        for (int mf = 0; mf < 4; ++mf)
            af[mf] = *(const short8*)&A[wm * 64 + mf * 16 + l0][ks * 32 + 8 * g];
#pragma unroll
        for (int nf = 0; nf < 4; ++nf)
            bfr[nf] = *(const short8*)(Fb + (size_t)(ks * 16 + nf) * 512);
#pragma unroll
        for (int mf = 0; mf < 4; ++mf)
#pragma unroll
            for (int nf = 0; nf < 4; ++nf)
                acc[mf][nf] = __builtin_amdgcn_mfma_f32_16x16x32_bf16(af[mf], bfr[nf], acc[mf][nf], 0, 0, 0);
    }

    __syncthreads();   // all A reads done; reuse as C-stage
    us (*Cs)[136] = A;
#pragma unroll
    for (int nf = 0; nf < 4; ++nf) {
        int lcol = wn * 64 + nf * 16 + l0;
        float bgv = (mat == 3) ? bg[lc0 + lcol] : 0.0f;
#pragma unroll
        for (int mf = 0; mf < 4; ++mf) {
#pragma unroll
            for (int r = 0; r < 4; ++r) {
                float v = acc[mf][nf][r];
                if (mat == 3) v = 1.0f / (1.0f + __expf(-(v + bgv)));
                Cs[wm * 64 + mf * 16 + 4 * g + r][lcol] = bfc(v);
            }
        }
    }
    __syncthreads();

    // coalesced write: 256B per row
#pragma unroll
    for (int e = 0; e < 8; ++e) {
        int cid = e * 256 + t;
        int row = cid >> 4, c = cid & 15;
        short8 vv = *(const short8*)&Cs[row][c * 8];
        *(short8*)(P + (size_t)(m0 + row) * 1024 + mat * 256 + lc0 + c * 8) = vv;
    }
}

// ---------------- K3: MFMA attention per (i,h), bf16 P ----------------------
__global__ __launch_bounds__(256) void k_attn(us* __restrict__ P,
                                              const float* __restrict__ djk,
                                              const float* __restrict__ Wd,
                                              const float* __restrict__ mask)
{
    const int i = blockIdx.x, h = blockIdx.y, t = threadIdx.x;
    const size_t rowbase = (size_t)i * LL * 1024;
    const int hoff = h * CC;
    __shared__ us ksl[LL][40];    // K, perm-d; reused as gated C-stage
    __shared__ us vt[CC][264];    // V^T, perm-k per 32-block
    __shared__ float madd[LL];

#pragma unroll
    for (int e = 0; e < 4; ++e) {
        int cid = e * 256 + t;
        int row = cid >> 2, c = cid & 3;
        uint4 q = *(const uint4*)(P + rowbase + (size_t)row * 1024 + 256 + hoff + c * 8);
        int fe = (c & 1) * 16 + (c >> 1) * 4;
        *(uint2*)&ksl[row][fe]     = make_uint2(q.x, q.y);
        *(uint2*)&ksl[row][fe + 8] = make_uint2(q.z, q.w);
    }
#pragma unroll
    for (int e = 0; e < 4; ++e) {
        int cid = e * 256 + t;
        int r = cid >> 2, c = cid & 3;
        short8 vv = *(const short8*)(P + rowbase + (size_t)r * 1024 + 512 + hoff + c * 8);
        int kk = r & 31;
        int pos = (r >> 5) * 32 + 8 * ((kk & 15) >> 2) + 4 * (kk >> 4) + (kk & 3);
#pragma unroll
        for (int u = 0; u < 8; ++u)
            vt[c * 8 + u][pos] = (us)vv[u];
    }
    madd[t] = 1e9f * (mask[i * LL + t] - 1.0f);

    const int lane = t & 63, w = t >> 6;
    const int l0 = lane & 15, g = lane >> 4;
    const int q0 = w * 64;
    const float wd = Wd[h];

    short8 qf[4];
    const float* djk_q[4];
    int qrow[4];
#pragma unroll
    for (int qt = 0; qt < 4; ++qt) {
        qrow[qt] = q0 + qt * 16 + l0;
        djk_q[qt] = djk + (size_t)qrow[qt] * LL;
        const us* qb = P + rowbase + (size_t)qrow[qt] * 1024 + hoff;
        short4v a = *(const short4v*)(qb + 4 * g);
        short4v b = *(const short4v*)(qb + 16 + 4 * g);
        qf[qt][0] = a.x; qf[qt][1] = a.y; qf[qt][2] = a.z; qf[qt][3] = a.w;
        qf[qt][4] = b.x; qf[qt][5] = b.y; qf[qt][6] = b.z; qf[qt][7] = b.w;
    }
    __syncthreads();

    f32x4 oacc[2][4];
#pragma unroll
    for (int ct = 0; ct < 2; ++ct)
#pragma unroll
        for (int qt = 0; qt < 4; ++qt) oacc[ct][qt] = (f32x4){0, 0, 0, 0};
    float ssum[4] = {0, 0, 0, 0};

    for (int p = 0; p < 8; ++p) {
        us pf[4][2][4];
#pragma unroll
        for (int half = 0; half < 2; ++half) {
            const int kt = 2 * p + half;
            const int krow = kt * 16 + l0;
            short8 kf = *(const short8*)&ksl[krow][8 * g];
            f32x4 mvv = *(const f32x4*)&madd[kt * 16 + 4 * g];
#pragma unroll
            for (int qt = 0; qt < 4; ++qt) {
                f32x4 z4 = {0, 0, 0, 0};
                f32x4 s = __builtin_amdgcn_mfma_f32_16x16x32_bf16(kf, qf[qt], z4, 0, 0, 0);
                f32x4 dv = *(const f32x4*)(djk_q[qt] + kt * 16 + 4 * g);
                float p0 = __expf(s[0] + wd * dv.x + mvv.x);
                float p1 = __expf(s[1] + wd * dv.y + mvv.y);
                float p2 = __expf(s[2] + wd * dv.z + mvv.z);
                float p3 = __expf(s[3] + wd * dv.w + mvv.w);
                ssum[qt] += (p0 + p1) + (p2 + p3);
                pf[qt][half][0] = bfc(p0); pf[qt][half][1] = bfc(p1);
                pf[qt][half][2] = bfc(p2); pf[qt][half][3] = bfc(p3);
            }
        }
#pragma unroll
        for (int ct = 0; ct < 2; ++ct) {
            short8 vf = *(const short8*)&vt[ct * 16 + l0][32 * p + 8 * g];
#pragma unroll
            for (int qt = 0; qt < 4; ++qt) {
                short8 pfr;
#pragma unroll
                for (int j = 0; j < 4; ++j) {
                    pfr[j]     = (short)pf[qt][0][j];
                    pfr[j + 4] = (short)pf[qt][1][j];
                }
                oacc[ct][qt] = __builtin_amdgcn_mfma_f32_16x16x32_bf16(vf, pfr, oacc[ct][qt], 0, 0, 0);
            }
        }
    }

    // epilogue: row sums, gate, stage via LDS (reuse ksl), coalesced write
    __syncthreads();
    us (*gs)[40] = (us (*)[40])ksl;
#pragma unroll
    for (int qt = 0; qt < 4; ++qt) {
        float s = ssum[qt];
        s += __shfl_xor(s, 16, 64);
        s += __shfl_xor(s, 32, 64);
        float inv = 1.0f / s;
        const us* base = P + rowbase + (size_t)qrow[qt] * 1024 + hoff;
#pragma unroll
        for (int ct = 0; ct < 2; ++ct) {
            short4v gv = *(const short4v*)(base + 768 + ct * 16 + 4 * g);
            f32x4 ov = oacc[ct][qt];
            short4v res;
            res.x = (short)bfc(bf2f((us)gv.x) * ov.x * inv);
            res.y = (short)bfc(bf2f((us)gv.y) * ov.y * inv);
            res.z = (short)bfc(bf2f((us)gv.z) * ov.z * inv);
            res.w = (short)bfc(bf2f((us)gv.w) * ov.w * inv);
            *(short4v*)&gs[qrow[qt]][ct * 16 + 4 * g] = res;
        }
    }
    __syncthreads();
#pragma unroll
    for (int e = 0; e < 4; ++e) {
        int cid = e * 256 + t;
        int row = cid >> 2, c = cid & 3;
        short8 vv = *(const short8*)&gs[row][c * 8];
        *(short8*)(P + rowbase + (size_t)row * 1024 + hoff + c * 8) = vv;
    }
}

// ---------------- K4: out = gated @ (WfH + WfL) + bf, x mask (MFMA) ---------
__global__ __launch_bounds__(256) void k_out(const us* __restrict__ P,
                                             const us* __restrict__ WfpH,
                                             const us* __restrict__ WfpL,
                                             const float* __restrict__ bf_,
                                             const float* __restrict__ mask,
                                             float* __restrict__ out)
{
    const int t = threadIdx.x;
    const int m0 = blockIdx.x * 64;
    __shared__ us A[64][264];
#pragma unroll
    for (int e = 0; e < 8; ++e) {
        int cid = e * 256 + t;
        int row = cid >> 5, c = cid & 31;
        uint4 q = *(const uint4*)(P + (size_t)(m0 + row) * 1024 + c * 8);
        int ksb = c >> 2, cc = c & 3;
        int fe = (cc & 1) * 16 + (cc >> 1) * 4;
        *(uint2*)&A[row][ksb * 32 + fe]     = make_uint2(q.x, q.y);
        *(uint2*)&A[row][ksb * 32 + fe + 8] = make_uint2(q.z, q.w);
    }
    __syncthreads();
    const int lane = t & 63, w = t >> 6;
    const int l0 = lane & 15, g = lane >> 4;
    f32x4 acc[8];
#pragma unroll
    for (int nf = 0; nf < 8; ++nf) acc[nf] = (f32x4){0, 0, 0, 0};

#pragma unroll
    for (int ksb = 0; ksb < 8; ++ksb) {
        short8 af = *(const short8*)&A[w * 16 + l0][ksb * 32 + 8 * g];
#pragma unroll
        for (int nf = 0; nf < 8; ++nf) {
            short8 bh = *(const short8*)(WfpH + ((size_t)(ksb * 8 + nf) * 64 + lane) * 8);
            short8 bl = *(const short8*)(WfpL + ((size_t)(ksb * 8 + nf) * 64 + lane) * 8);
            acc[nf] = __builtin_amdgcn_mfma_f32_16x16x32_bf16(af, bh, acc[nf], 0, 0, 0);
            acc[nf] = __builtin_amdgcn_mfma_f32_16x16x32_bf16(af, bl, acc[nf], 0, 0, 0);
        }
    }
    float maskv[4];
    int rowm[4];
#pragma unroll
    for (int r = 0; r < 4; ++r) {
        rowm[r] = m0 + w * 16 + 4 * g + r;
        maskv[r] = mask[rowm[r]];
    }
#pragma unroll
    for (int nf = 0; nf < 8; ++nf) {
        int n = nf * 16 + l0;
        float bfv = bf_[n];
#pragma unroll
        for (int r = 0; r < 4; ++r)
            out[(size_t)rowm[r] * DD + n] = (acc[nf][r] + bfv) * maskv[r];
    }
}

extern "C" void kernel_launch(void* const* d_in, const int* in_sizes, int n_in,
                              void* d_out, int out_size, void* d_ws, size_t ws_size,
                              hipStream_t stream)
{
    const float* z     = (const float*)d_in[0];
    const float* djk   = (const float*)d_in[1];
    const float* mask  = (const float*)d_in[2];
    const float* gamma = (const float*)d_in[3];
    const float* beta  = (const float*)d_in[4];
    const float* Wq    = (const float*)d_in[5];
    const float* Wk    = (const float*)d_in[6];
    const float* Wv    = (const float*)d_in[7];
    // d_in[8] = Wb: constant along softmax axis -> cancels exactly.
    const float* Wd    = (const float*)d_in[9];
    const float* Wg    = (const float*)d_in[10];
    const float* bg    = (const float*)d_in[11];
    const float* Wf    = (const float*)d_in[12];
    const float* bf_   = (const float*)d_in[13];
    float* out = (float*)d_out;

    us* zn   = (us*)d_ws;                        // 8.4 MB
    us* P    = zn + (size_t)NROW * DD;           // 67 MB
    us* WfpH = P + (size_t)NROW * 1024;          // 64 KB
    us* WfpL = WfpH + 256 * 128;                 // 64 KB
    us* F    = WfpL + 256 * 128;                 // 256 KB (qkvg frags)

    k_ln   <<<NROW / 4, 256, 0, stream>>>(z, gamma, beta, zn);
    k_wprep<<<160, 256, 0, stream>>>(Wq, Wk, Wv, Wg, Wf, F, WfpH, WfpL);
    k_proj <<<dim3(NROW / 128, 8), 256, 0, stream>>>(zn, F, bg, P);
    k_attn <<<dim3(II, HH), 256, 0, stream>>>(P, djk, Wd, mask);
    k_out  <<<NROW / 64, 256, 0, stream>>>(P, WfpH, WfpL, bf_, mask, out);
}

// Round 6
// 102.355 us; speedup vs baseline: 5.1616x; 1.0481x over previous
//
#include <hip/hip_runtime.h>
#include <hip/hip_bf16.h>
#include <math.h>

#define HH 8
#define CC 32
#define DD 128
#define HC 256
#define II 128
#define LL 256
#define NROW (II*LL)   // 32768
#define LN_EPS 1e-5f

typedef float f32x4 __attribute__((ext_vector_type(4)));
typedef short short8 __attribute__((ext_vector_type(8)));
typedef short short4v __attribute__((ext_vector_type(4)));
typedef unsigned short us;

static __device__ __forceinline__ us bfc(float x) {
    return __builtin_bit_cast(us, __float2bfloat16(x));
}
static __device__ __forceinline__ float bf2f(us h) {
    return __builtin_bit_cast(float, ((unsigned int)h) << 16);
}

// ---------------- K1: LayerNorm, 1 wave per row, bf16 out -------------------
__global__ __launch_bounds__(256) void k_ln(const float* __restrict__ z,
                                            const float* __restrict__ gamma,
                                            const float* __restrict__ beta,
                                            us* __restrict__ zn)
{
    const int t = threadIdx.x;
    const int row = blockIdx.x * 4 + (t >> 6);
    const int lane = t & 63;
    float2 x = *(const float2*)(z + (size_t)row * DD + lane * 2);
    float s = x.x + x.y;
    float s2 = x.x * x.x + x.y * x.y;
#pragma unroll
    for (int off = 1; off < 64; off <<= 1) {
        s  += __shfl_xor(s, off, 64);
        s2 += __shfl_xor(s2, off, 64);
    }
    float mu = s * (1.0f / DD);
    float var = s2 * (1.0f / DD) - mu * mu;
    float rstd = rsqrtf(var + LN_EPS);
    float2 gm = *(const float2*)(gamma + lane * 2);
    float2 bt = *(const float2*)(beta + lane * 2);
    float y0 = (x.x - mu) * rstd * gm.x + bt.x;
    float y1 = (x.y - mu) * rstd * gm.y + bt.y;
    unsigned int pk = (unsigned int)bfc(y0) | ((unsigned int)bfc(y1) << 16);
    ((unsigned int*)zn)[(size_t)row * 64 + lane] = pk;
}

// ---------------- K1b: weight prep (unchanged) ------------------------------
__global__ __launch_bounds__(256) void k_wprep(const float* __restrict__ Wq,
                                               const float* __restrict__ Wk,
                                               const float* __restrict__ Wv,
                                               const float* __restrict__ Wg,
                                               const float* __restrict__ Wf,
                                               us* __restrict__ F,
                                               us* __restrict__ WfpH,
                                               us* __restrict__ WfpL)
{
    const int bid = blockIdx.x;
    if (bid < 128) {
        const int mat = bid >> 5;
        const float* W = (mat == 0) ? Wq : (mat == 1) ? Wk : (mat == 2) ? Wv : Wg;
        const float scale = (mat == 0) ? 0.35355339059327373f : 1.0f;
        int base = (bid & 31) * 1024 + threadIdx.x * 4;
        float4 wv = *(const float4*)(W + base);
        int k = base >> 8, n0 = base & 255;
        int ks = k >> 5, kk = k & 31;
        int slot = ((kk >> 4) << 2) | (kk & 3);
        int gg = (kk >> 2) & 3;
        float vals[4] = {wv.x, wv.y, wv.z, wv.w};
        us* Fb = F + mat * 32768;
#pragma unroll
        for (int e = 0; e < 4; ++e) {
            int n = n0 + e;
            int lane = (n & 15) | (gg << 4);
            Fb[((size_t)(ks * 16 + (n >> 4)) * 64 + lane) * 8 + slot] = bfc(vals[e] * scale);
        }
    } else {
        int idx = ((bid - 128) * 256 + threadIdx.x) * 4;
#pragma unroll
        for (int e = 0; e < 4; ++e, ++idx) {
            int k = idx >> 7, n = idx & 127;
            float w = Wf[idx];
            us hi = bfc(w);
            us lo = bfc(w - bf2f(hi));
            int kk = k & 31;
            int g = (kk >> 2) & 3, b = kk >> 4, j0 = kk & 3;
            int lane = (n & 15) | (g << 4);
            size_t dst = ((size_t)((k >> 5) * 8 + (n >> 4)) * 64 + lane) * 8 + b * 4 + j0;
            WfpH[dst] = hi;
            WfpL[dst] = lo;
        }
    }
}

// ---------------- K2: projections via bf16 MFMA ------------------------------
// Outputs:
//  Qf/Kf[ih][kt(16)][lane(64)][8]: frag slot j of lane (l0,g) = X[i][kt*16+l0][h*32+8g+j]
//  Vtf[ih][p(8)][ct(2)][lane(64)][8]: slot j = V[i][32p+4g+(j&3)+16*(j>>2)][h*32+ct*16+l0]
//  Pg[row][256]: sigmoid gate, row layout
__global__ __launch_bounds__(256, 4) void k_proj(const us* __restrict__ zn,
                                                 const us* __restrict__ F,
                                                 const float* __restrict__ bg,
                                                 us* __restrict__ Qf,
                                                 us* __restrict__ Kf,
                                                 us* __restrict__ Vtf,
                                                 us* __restrict__ Pg)
{
    const int rb = blockIdx.x, cb = blockIdx.y, t = threadIdx.x;
    const int m0 = rb * 128, n0 = cb * 128;
    const int mat = n0 >> 8, lc0 = n0 & 255;
    __shared__ us A[128][136];   // perm-k A tile; reused as C-stage

    // A stage: 16B chunks -> perm positions
#pragma unroll
    for (int e = 0; e < 8; ++e) {
        int cid = e * 256 + t;
        int row = cid >> 4, c = cid & 15;
        uint4 q = *(const uint4*)(zn + (size_t)(m0 + row) * DD + c * 8);
        int ks = c >> 2, cc = c & 3;
        int fe = (cc & 1) * 16 + (cc >> 1) * 4;
        *(uint2*)&A[row][ks * 32 + fe]     = make_uint2(q.x, q.y);
        *(uint2*)&A[row][ks * 32 + fe + 8] = make_uint2(q.z, q.w);
    }
    __syncthreads();

    const int lane = t & 63, w = t >> 6;
    const int wm = w & 1, wn = w >> 1;
    const int l0 = lane & 15, g = lane >> 4;
    const us* Fb = F + mat * 32768 + ((size_t)((lc0 >> 4) + wn * 4) * 64 + lane) * 8;
    f32x4 acc[4][4];
#pragma unroll
    for (int a = 0; a < 4; ++a)
#pragma unroll
        for (int b = 0; b < 4; ++b) acc[a][b] = (f32x4){0, 0, 0, 0};

#pragma unroll
    for (int ks = 0; ks < 4; ++ks) {
        short8 af[4], bfr[4];
#pragma unroll
        for (int mf = 0; mf < 4; ++mf)
            af[mf] = *(const short8*)&A[wm * 64 + mf * 16 + l0][ks * 32 + 8 * g];
#pragma unroll
        for (int nf = 0; nf < 4; ++nf)
            bfr[nf] = *(const short8*)(Fb + (size_t)(ks * 16 + nf) * 512);
#pragma unroll
        for (int mf = 0; mf < 4; ++mf)
#pragma unroll
            for (int nf = 0; nf < 4; ++nf)
                acc[mf][nf] = __builtin_amdgcn_mfma_f32_16x16x32_bf16(af[mf], bfr[nf], acc[mf][nf], 0, 0, 0);
    }

    __syncthreads();   // all A reads done; reuse as C-stage (plain row/col)
    us (*Cs)[136] = A;
#pragma unroll
    for (int nf = 0; nf < 4; ++nf) {
        int lcol = wn * 64 + nf * 16 + l0;
        float bgv = (mat == 3) ? bg[lc0 + lcol] : 0.0f;
#pragma unroll
        for (int mf = 0; mf < 4; ++mf) {
#pragma unroll
            for (int r = 0; r < 4; ++r) {
                float v = acc[mf][nf][r];
                if (mat == 3) v = 1.0f / (1.0f + __expf(-(v + bgv)));
                Cs[wm * 64 + mf * 16 + 4 * g + r][lcol] = bfc(v);
            }
        }
    }
    __syncthreads();

    const int i = m0 >> 8, half = (m0 >> 7) & 1;
    if (mat <= 1) {
        us* Dst = (mat == 0) ? Qf : Kf;
#pragma unroll
        for (int e = 0; e < 8; ++e) {               // FIX: 8 x 256 covers all 2048 chunks
            int sub = e * 256 + t;                  // 0..2047
            int lane2 = sub & 63;
            int l0b = lane2 & 15, gb = lane2 >> 4;
            int rest = sub >> 6;                    // 0..31
            int hl = rest & 3, ktl = rest >> 2;     // 4 heads, 8 kt
            int hglob = (lc0 >> 5) + hl;
            int kt = half * 8 + ktl;
            short8 vv = *(const short8*)&Cs[ktl * 16 + l0b][hl * 32 + 8 * gb];
            *(short8*)(Dst + (((size_t)(i * 8 + hglob) * 16 + kt) * 64 + lane2) * 8) = vv;
        }
    } else if (mat == 2) {
#pragma unroll
        for (int e = 0; e < 8; ++e) {               // FIX: 8 x 256 covers all 2048 chunks
            int sub = e * 256 + t;                  // 0..2047
            int lane2 = sub & 63;
            int l0b = lane2 & 15, gb = lane2 >> 4;
            int rest = sub >> 6;                    // 0..31
            int ct = rest & 1, pl = (rest >> 1) & 3, hl = rest >> 3;
            int hglob = (lc0 >> 5) + hl;
            int p = half * 4 + pl;
            int col = hl * 32 + ct * 16 + l0b;
            us vals[8];
#pragma unroll
            for (int j = 0; j < 8; ++j) {
                int kk = 4 * gb + (j & 3) + 16 * (j >> 2);
                vals[j] = Cs[pl * 32 + kk][col];
            }
            *(short8*)(Vtf + ((((size_t)(i * 8 + hglob) * 8 + p) * 2 + ct) * 64 + lane2) * 8)
                = *(short8*)vals;
        }
    } else {
#pragma unroll
        for (int e = 0; e < 8; ++e) {
            int cid = e * 256 + t;
            int row = cid >> 4, c = cid & 15;
            short8 vv = *(const short8*)&Cs[row][c * 8];
            *(short8*)(Pg + (size_t)(m0 + row) * 256 + lc0 + c * 8) = vv;
        }
    }
}

// ---------------- K3: MFMA attention, all-fragment global loads -------------
// Grid (1024, 2): block = (ih, q-half of 128 rows); 4 waves x 32 q-rows.
__global__ __launch_bounds__(256) void k_attn(const us* __restrict__ Qf,
                                              const us* __restrict__ Kf,
                                              const us* __restrict__ Vtf,
                                              const us* __restrict__ Pg,
                                              us* __restrict__ Po,
                                              const float* __restrict__ djk,
                                              const float* __restrict__ Wd,
                                              const float* __restrict__ mask)
{
    const int ih = blockIdx.x, qh = blockIdx.y;
    const int i = ih >> 3, h = ih & 7;
    const int t = threadIdx.x;
    const int lane = t & 63, w = t >> 6;
    const int l0 = lane & 15, g = lane >> 4;
    const int q0 = qh * 128 + w * 32;
    __shared__ us gs[128][40];

    const float wd = Wd[h];
    const us* Qb = Qf + (size_t)ih * 8192;
    const us* Kb = Kf + (size_t)ih * 8192;
    const us* Vb = Vtf + (size_t)ih * 8192;

    short8 qfr[2];
    int qrow[2];
    const float* djkq[2];
#pragma unroll
    for (int qt = 0; qt < 2; ++qt) {
        qfr[qt] = *(const short8*)(Qb + ((size_t)((q0 >> 4) + qt) * 64 + lane) * 8);
        qrow[qt] = q0 + qt * 16 + l0;
        djkq[qt] = djk + (size_t)qrow[qt] * LL;
    }

    f32x4 oacc[2][2];
#pragma unroll
    for (int ct = 0; ct < 2; ++ct)
#pragma unroll
        for (int qt = 0; qt < 2; ++qt) oacc[ct][qt] = (f32x4){0, 0, 0, 0};
    float ssum[2] = {0, 0};

    for (int p = 0; p < 8; ++p) {
        short8 pfv[2];
#pragma unroll
        for (int hf = 0; hf < 2; ++hf) {
            const int kt = 2 * p + hf;
            short8 kfr = *(const short8*)(Kb + ((size_t)kt * 64 + lane) * 8);
            f32x4 mv = *(const f32x4*)(mask + i * LL + kt * 16 + 4 * g);
            float ma0 = 1e9f * (mv.x - 1.0f), ma1 = 1e9f * (mv.y - 1.0f);
            float ma2 = 1e9f * (mv.z - 1.0f), ma3 = 1e9f * (mv.w - 1.0f);
#pragma unroll
            for (int qt = 0; qt < 2; ++qt) {
                f32x4 z4 = {0, 0, 0, 0};
                f32x4 s = __builtin_amdgcn_mfma_f32_16x16x32_bf16(kfr, qfr[qt], z4, 0, 0, 0);
                f32x4 dv = *(const f32x4*)(djkq[qt] + kt * 16 + 4 * g);
                float p0 = __expf(s[0] + wd * dv.x + ma0);
                float p1 = __expf(s[1] + wd * dv.y + ma1);
                float p2 = __expf(s[2] + wd * dv.z + ma2);
                float p3 = __expf(s[3] + wd * dv.w + ma3);
                ssum[qt] += (p0 + p1) + (p2 + p3);
                pfv[qt][hf * 4 + 0] = (short)bfc(p0);
                pfv[qt][hf * 4 + 1] = (short)bfc(p1);
                pfv[qt][hf * 4 + 2] = (short)bfc(p2);
                pfv[qt][hf * 4 + 3] = (short)bfc(p3);
            }
        }
#pragma unroll
        for (int ct = 0; ct < 2; ++ct) {
            short8 vfr = *(const short8*)(Vb + ((size_t)(p * 2 + ct) * 64 + lane) * 8);
#pragma unroll
            for (int qt = 0; qt < 2; ++qt)
                oacc[ct][qt] = __builtin_amdgcn_mfma_f32_16x16x32_bf16(vfr, pfv[qt], oacc[ct][qt], 0, 0, 0);
        }
    }

    // epilogue: row sums, gate, LDS transpose, coalesced write
#pragma unroll
    for (int qt = 0; qt < 2; ++qt) {
        float s = ssum[qt];
        s += __shfl_xor(s, 16, 64);
        s += __shfl_xor(s, 32, 64);
        float inv = 1.0f / s;
        const us* gb = Pg + (size_t)(i * LL + qrow[qt]) * 256 + h * CC;
#pragma unroll
        for (int ct = 0; ct < 2; ++ct) {
            short4v gv = *(const short4v*)(gb + ct * 16 + 4 * g);
            f32x4 ov = oacc[ct][qt];
            short4v res;
            res.x = (short)bfc(bf2f((us)gv.x) * ov.x * inv);
            res.y = (short)bfc(bf2f((us)gv.y) * ov.y * inv);
            res.z = (short)bfc(bf2f((us)gv.z) * ov.z * inv);
            res.w = (short)bfc(bf2f((us)gv.w) * ov.w * inv);
            *(short4v*)&gs[w * 32 + qt * 16 + l0][ct * 16 + 4 * g] = res;
        }
    }
    __syncthreads();
#pragma unroll
    for (int e = 0; e < 2; ++e) {
        int cid = e * 256 + t;           // 0..511
        int row = cid >> 2, c = cid & 3;
        short8 vv = *(const short8*)&gs[row][c * 8];
        *(short8*)(Po + (size_t)(i * LL + qh * 128 + row) * 256 + h * CC + c * 8) = vv;
    }
}

// ---------------- K4: out = gated @ (WfH + WfL) + bf, x mask (MFMA) ---------
__global__ __launch_bounds__(256) void k_out(const us* __restrict__ Po,
                                             const us* __restrict__ WfpH,
                                             const us* __restrict__ WfpL,
                                             const float* __restrict__ bf_,
                                             const float* __restrict__ mask,
                                             float* __restrict__ out)
{
    const int t = threadIdx.x;
    const int m0 = blockIdx.x * 64;
    __shared__ us A[64][264];
#pragma unroll
    for (int e = 0; e < 8; ++e) {
        int cid = e * 256 + t;
        int row = cid >> 5, c = cid & 31;
        uint4 q = *(const uint4*)(Po + (size_t)(m0 + row) * 256 + c * 8);
        int ksb = c >> 2, cc = c & 3;
        int fe = (cc & 1) * 16 + (cc >> 1) * 4;
        *(uint2*)&A[row][ksb * 32 + fe]     = make_uint2(q.x, q.y);
        *(uint2*)&A[row][ksb * 32 + fe + 8] = make_uint2(q.z, q.w);
    }
    __syncthreads();
    const int lane = t & 63, w = t >> 6;
    const int l0 = lane & 15, g = lane >> 4;
    f32x4 acc[8];
#pragma unroll
    for (int nf = 0; nf < 8; ++nf) acc[nf] = (f32x4){0, 0, 0, 0};

#pragma unroll
    for (int ksb = 0; ksb < 8; ++ksb) {
        short8 af = *(const short8*)&A[w * 16 + l0][ksb * 32 + 8 * g];
#pragma unroll
        for (int nf = 0; nf < 8; ++nf) {
            short8 bh = *(const short8*)(WfpH + ((size_t)(ksb * 8 + nf) * 64 + lane) * 8);
            short8 bl = *(const short8*)(WfpL + ((size_t)(ksb * 8 + nf) * 64 + lane) * 8);
            acc[nf] = __builtin_amdgcn_mfma_f32_16x16x32_bf16(af, bh, acc[nf], 0, 0, 0);
            acc[nf] = __builtin_amdgcn_mfma_f32_16x16x32_bf16(af, bl, acc[nf], 0, 0, 0);
        }
    }
    float maskv[4];
    int rowm[4];
#pragma unroll
    for (int r = 0; r < 4; ++r) {
        rowm[r] = m0 + w * 16 + 4 * g + r;
        maskv[r] = mask[rowm[r]];
    }
#pragma unroll
    for (int nf = 0; nf < 8; ++nf) {
        int n = nf * 16 + l0;
        float bfv = bf_[n];
#pragma unroll
        for (int r = 0; r < 4; ++r)
            out[(size_t)rowm[r] * DD + n] = (acc[nf][r] + bfv) * maskv[r];
    }
}

extern "C" void kernel_launch(void* const* d_in, const int* in_sizes, int n_in,
                              void* d_out, int out_size, void* d_ws, size_t ws_size,
                              hipStream_t stream)
{
    const float* z     = (const float*)d_in[0];
    const float* djk   = (const float*)d_in[1];
    const float* mask  = (const float*)d_in[2];
    const float* gamma = (const float*)d_in[3];
    const float* beta  = (const float*)d_in[4];
    const float* Wq    = (const float*)d_in[5];
    const float* Wk    = (const float*)d_in[6];
    const float* Wv    = (const float*)d_in[7];
    // d_in[8] = Wb: constant along softmax axis -> cancels exactly.
    const float* Wd    = (const float*)d_in[9];
    const float* Wg    = (const float*)d_in[10];
    const float* bg    = (const float*)d_in[11];
    const float* Wf    = (const float*)d_in[12];
    const float* bf_   = (const float*)d_in[13];
    float* out = (float*)d_out;

    us* zn   = (us*)d_ws;                         // 8.4 MB
    us* Qf   = zn   + (size_t)NROW * DD;          // 16.8 MB
    us* Kf   = Qf   + (size_t)1024 * 8192;        // 16.8 MB
    us* Vtf  = Kf   + (size_t)1024 * 8192;        // 16.8 MB
    us* Pg   = Vtf  + (size_t)1024 * 8192;        // 16.8 MB
    us* Po   = Pg   + (size_t)NROW * 256;         // 16.8 MB
    us* WfpH = Po   + (size_t)NROW * 256;         // 64 KB
    us* WfpL = WfpH + 256 * 128;                  // 64 KB
    us* F    = WfpL + 256 * 128;                  // 256 KB

    k_ln   <<<NROW / 4, 256, 0, stream>>>(z, gamma, beta, zn);
    k_wprep<<<160, 256, 0, stream>>>(Wq, Wk, Wv, Wg, Wf, F, WfpH, WfpL);
    k_proj <<<dim3(NROW / 128, 8), 256, 0, stream>>>(zn, F, bg, Qf, Kf, Vtf, Pg);
    k_attn <<<dim3(II * HH, 2), 256, 0, stream>>>(Qf, Kf, Vtf, Pg, Po, djk, Wd, mask);
    k_out  <<<NROW / 64, 256, 0, stream>>>(Po, WfpH, WfpL, bf_, mask, out);
}